// Round 4
// baseline (138.831 us; speedup 1.0000x reference)
//
#include <hip/hip_runtime.h>
#include <hip/hip_bf16.h>

#define HIDDEN 2048
#define NT 32          // K tiles of 64
#define BK 64
#define LDS_BYTES 132096  // 2x32KB A + 2x32KB B + 1KB dummy sink

typedef __attribute__((ext_vector_type(8))) short bf16x8;
typedef __attribute__((ext_vector_type(4))) float f32x4;
typedef __attribute__((ext_vector_type(8))) unsigned short u16x8;

#define GLDS(gptr, lptr)                                                       \
    __builtin_amdgcn_global_load_lds(                                          \
        (const __attribute__((address_space(1))) void*)(gptr),                 \
        (__attribute__((address_space(3))) void*)(lptr), 16, 0, 0)

#define SCHED0() __builtin_amdgcn_sched_barrier(0)
#define BARRIER() __builtin_amdgcn_s_barrier()
#define LGKM0() do { asm volatile("s_waitcnt lgkmcnt(0)" ::: "memory"); SCHED0(); } while (0)
#define VMCNT(n) asm volatile("s_waitcnt vmcnt(" #n ")" ::: "memory")

// ---- Build dense W (f32) from COO with duplicate summing ----
__global__ void build_w_kernel(const float* __restrict__ vals,
                               const int* __restrict__ rows,
                               const int* __restrict__ cols,
                               float* __restrict__ W, int nnz) {
    int k = blockIdx.x * blockDim.x + threadIdx.x;
    if (k < nnz) atomicAdd(&W[(size_t)rows[k] * HIDDEN + cols[k]], vals[k]);
}

// ---- f32 -> bf16(trunc), 8 elems/thread, grid-stride ----
__global__ void convert_kernel(const float* __restrict__ src,
                               unsigned short* __restrict__ dst, int n8) {
    int i = blockIdx.x * blockDim.x + threadIdx.x;
    const int stride = gridDim.x * blockDim.x;
    for (; i < n8; i += stride) {
        f32x4 a = ((const f32x4*)src)[2 * i];
        f32x4 b = ((const f32x4*)src)[2 * i + 1];
        u16x8 h;
        #pragma unroll
        for (int j = 0; j < 4; ++j) {
            h[j]     = (unsigned short)(__float_as_uint(a[j]) >> 16);
            h[4 + j] = (unsigned short)(__float_as_uint(b[j]) >> 16);
        }
        ((u16x8*)dst)[i] = h;
    }
}

// ---- 256x256x64 8-wave 4-phase GEMM: out = xc + alpha * (xp @ W^T) ----
__global__ __launch_bounds__(512, 2) void gemm_kernel(
    const float* __restrict__ xc,
    const unsigned short* __restrict__ xpb,   // bf16 [8192][2048]
    const unsigned short* __restrict__ Wb,    // bf16 [2048][2048]
    const float* __restrict__ alpha_p,
    float* __restrict__ out)
{
    extern __shared__ __align__(16) char lds[];
    char* const ldsA = lds;             // [2 bufs][2 halves 16KB] = 64KB
    char* const ldsB = lds + 65536;     // 64KB
    char* const ldsX = lds + 131072;    // 1KB dummy sink for tail staging

    const int tid  = threadIdx.x;
    const int lane = tid & 63;
    const int wave = tid >> 6;
    const int l15  = lane & 15;
    const int l4   = lane >> 4;

    // XCD-chunked bijective mapping: XCD x (= bid%8, HW round-robin) owns a
    // 4m x 8n chunk -> per-K-tile slice (12 panels x 32KB = 384KB) is L2-resident;
    // each A panel is fetched by exactly ONE XCD.
    const int xcd = blockIdx.x & 7;
    const int loc = blockIdx.x >> 3;
    const int m0  = (xcd * 4 + (loc >> 3)) * 256;
    const int n0  = (loc & 7) * 256;

    const int wm = (wave >> 2) * 128;   // 2 M-waves
    const int wn = (wave & 3) * 64;     // 4 N-waves

    // ---- staging: per half-tile (128 rows x 64 cols bf16 = 1024 16B chunks),
    // wave covers rows wave*16 + {0..15}; row = lane>>3; slot = lane&7.
    // T2 swizzle: LDS dest linear, global SOURCE slot XOR'd with row&7.
    const int srow  = lane >> 3;
    const int sslot = (lane & 7) ^ srow;
    const unsigned short* const gA0 = xpb + (size_t)(m0 + wave * 16 + 0 + srow) * HIDDEN + sslot * 8;
    const unsigned short* const gA1 = xpb + (size_t)(m0 + wave * 16 + 8 + srow) * HIDDEN + sslot * 8;
    const unsigned short* const gB0 = Wb  + (size_t)(n0 + wave * 16 + 0 + srow) * HIDDEN + sslot * 8;
    const unsigned short* const gB1 = Wb  + (size_t)(n0 + wave * 16 + 8 + srow) * HIDDEN + sslot * 8;

    // Stage ALL 4 half-tiles (8 loads) of tile t. Legal only when buffer (t&1)
    // is fully consumed (end of phase 3 of tile t-2). Uniform 4-phase distance.
#define STAGE_ALL(t)                                                           \
    do {                                                                       \
        const int _t = (t);                                                    \
        if (_t < NT) {                                                         \
            const size_t _o  = (size_t)_t * BK;                                \
            const size_t _oh = _o + (size_t)128 * HIDDEN;                      \
            char* const _dA = ldsA + (_t & 1) * 32768 + wave * 2048;           \
            char* const _dB = ldsB + (_t & 1) * 32768 + wave * 2048;           \
            GLDS(gA0 + _o,  _dA);                                              \
            GLDS(gA1 + _o,  _dA + 1024);                                       \
            GLDS(gA0 + _oh, _dA + 16384);                                      \
            GLDS(gA1 + _oh, _dA + 16384 + 1024);                               \
            GLDS(gB0 + _o,  _dB);                                              \
            GLDS(gB1 + _o,  _dB + 1024);                                       \
            GLDS(gB0 + _oh, _dB + 16384);                                      \
            GLDS(gB1 + _oh, _dB + 16384 + 1024);                               \
        } else {                                                               \
            GLDS(gA0, ldsX); GLDS(gA0, ldsX); GLDS(gA0, ldsX); GLDS(gA0, ldsX);\
            GLDS(gA0, ldsX); GLDS(gA0, ldsX); GLDS(gA0, ldsX); GLDS(gA0, ldsX);\
        }                                                                      \
    } while (0)

    // ---- ds_read addressing (swizzled to match staging) ----
    const int swz  = l15 & 7;
    const int sk0  = ((l4 + 0) ^ swz) * 16;
    const int sk1  = ((l4 + 4) ^ swz) * 16;
    const int rowb = l15 * 128;
    const char* const AwaveBase = ldsA + (wm >> 7) * 16384;
    const char* const BwaveBase = ldsB + (wn >> 7) * 16384 + ((wn & 64) << 7);

    f32x4 acc[8][4] = {};   // [mi 0..7][nj 0..3]

    // ---- prologue: stage tiles 0 and 1 fully; vmcnt(8) -> tile 0 ready ----
    STAGE_ALL(0);
    STAGE_ALL(1);
    VMCNT(8);
    SCHED0(); BARRIER(); SCHED0();

    for (int tt = 0; tt < NT; ++tt) {
        const int c = tt & 1;
        const char* const Aw = AwaveBase + c * 32768;
        const char* const Bw = BwaveBase + c * 32768;

        bf16x8 a0[4][2], a1[4][2], b0[2][2], b1[2][2];

        // ======== Phase 1: read a0(8)+b0(4) | MFMA M0N0 ========
        #pragma unroll
        for (int mi = 0; mi < 4; ++mi) {
            a0[mi][0] = *(const bf16x8*)(Aw + mi * 2048 + rowb + sk0);
            a0[mi][1] = *(const bf16x8*)(Aw + mi * 2048 + rowb + sk1);
        }
        #pragma unroll
        for (int nj = 0; nj < 2; ++nj) {
            b0[nj][0] = *(const bf16x8*)(Bw + nj * 2048 + rowb + sk0);
            b0[nj][1] = *(const bf16x8*)(Bw + nj * 2048 + rowb + sk1);
        }
        SCHED0(); BARRIER();
        LGKM0();
        __builtin_amdgcn_s_setprio(1);
        #pragma unroll
        for (int mi = 0; mi < 4; ++mi)
            #pragma unroll
            for (int nj = 0; nj < 2; ++nj) {
                acc[mi][nj] = __builtin_amdgcn_mfma_f32_16x16x32_bf16(a0[mi][0], b0[nj][0], acc[mi][nj], 0, 0, 0);
                acc[mi][nj] = __builtin_amdgcn_mfma_f32_16x16x32_bf16(a0[mi][1], b0[nj][1], acc[mi][nj], 0, 0, 0);
            }
        __builtin_amdgcn_s_setprio(0);
        SCHED0(); BARRIER(); SCHED0();

        // ======== Phase 2: read b1(4) | MFMA M0N1 ========
        #pragma unroll
        for (int nj = 0; nj < 2; ++nj) {
            b1[nj][0] = *(const bf16x8*)(Bw + (2 + nj) * 2048 + rowb + sk0);
            b1[nj][1] = *(const bf16x8*)(Bw + (2 + nj) * 2048 + rowb + sk1);
        }
        SCHED0(); BARRIER();
        LGKM0();
        __builtin_amdgcn_s_setprio(1);
        #pragma unroll
        for (int mi = 0; mi < 4; ++mi)
            #pragma unroll
            for (int nj = 0; nj < 2; ++nj) {
                acc[mi][2 + nj] = __builtin_amdgcn_mfma_f32_16x16x32_bf16(a0[mi][0], b1[nj][0], acc[mi][2 + nj], 0, 0, 0);
                acc[mi][2 + nj] = __builtin_amdgcn_mfma_f32_16x16x32_bf16(a0[mi][1], b1[nj][1], acc[mi][2 + nj], 0, 0, 0);
            }
        __builtin_amdgcn_s_setprio(0);
        SCHED0(); BARRIER(); SCHED0();

        // ======== Phase 3: read a1(8) | MFMA M1N1 ========  (last LDS reads of buf c)
        #pragma unroll
        for (int mi = 0; mi < 4; ++mi) {
            a1[mi][0] = *(const bf16x8*)(Aw + (4 + mi) * 2048 + rowb + sk0);
            a1[mi][1] = *(const bf16x8*)(Aw + (4 + mi) * 2048 + rowb + sk1);
        }
        SCHED0(); BARRIER();
        LGKM0();
        __builtin_amdgcn_s_setprio(1);
        #pragma unroll
        for (int mi = 0; mi < 4; ++mi)
            #pragma unroll
            for (int nj = 0; nj < 2; ++nj) {
                acc[4 + mi][2 + nj] = __builtin_amdgcn_mfma_f32_16x16x32_bf16(a1[mi][0], b1[nj][0], acc[4 + mi][2 + nj], 0, 0, 0);
                acc[4 + mi][2 + nj] = __builtin_amdgcn_mfma_f32_16x16x32_bf16(a1[mi][1], b1[nj][1], acc[4 + mi][2 + nj], 0, 0, 0);
            }
        __builtin_amdgcn_s_setprio(0);
        SCHED0(); BARRIER(); SCHED0();

        // ======== Phase 4: stage ALL of tile t+2 | vmcnt(8) (t+1 arrived) | MFMA M1N0 ========
        STAGE_ALL(tt + 2);
        VMCNT(8);
        SCHED0(); BARRIER();
        __builtin_amdgcn_s_setprio(1);
        #pragma unroll
        for (int mi = 0; mi < 4; ++mi)
            #pragma unroll
            for (int nj = 0; nj < 2; ++nj) {
                acc[4 + mi][nj] = __builtin_amdgcn_mfma_f32_16x16x32_bf16(a1[mi][0], b0[nj][0], acc[4 + mi][nj], 0, 0, 0);
                acc[4 + mi][nj] = __builtin_amdgcn_mfma_f32_16x16x32_bf16(a1[mi][1], b0[nj][1], acc[4 + mi][nj], 0, 0, 0);
            }
        __builtin_amdgcn_s_setprio(0);
        SCHED0(); BARRIER(); SCHED0();
    }

    VMCNT(0);   // drain tail dummy loads

    // ---- epilogue: out = xc + alpha * acc ----
    const float alpha = alpha_p[0];
    #pragma unroll
    for (int mi = 0; mi < 8; ++mi) {
        #pragma unroll
        for (int r = 0; r < 4; ++r) {
            const int m = m0 + wm + mi * 16 + l4 * 4 + r;
            #pragma unroll
            for (int nj = 0; nj < 4; ++nj) {
                const int n = n0 + wn + nj * 16 + l15;
                const size_t o = (size_t)m * HIDDEN + n;
                out[o] = xc[o] + alpha * acc[mi][nj][r];
            }
        }
    }
#undef STAGE_ALL
}

extern "C" void kernel_launch(void* const* d_in, const int* in_sizes, int n_in,
                              void* d_out, int out_size, void* d_ws, size_t ws_size,
                              hipStream_t stream) {
    const float* xc    = (const float*)d_in[0];
    const float* xp    = (const float*)d_in[1];
    const float* alpha = (const float*)d_in[2];
    const float* vals  = (const float*)d_in[3];
    const int*   idx   = (const int*)d_in[4];
    float* out = (float*)d_out;

    float*          W   = (float*)d_ws;                                   // 16 MB
    unsigned short* Wb  = (unsigned short*)((char*)d_ws + (16 << 20));    //  8 MB
    unsigned short* xpb = (unsigned short*)((char*)d_ws + (24 << 20));    // 32 MB

    const int nnz = in_sizes[3];
    const int M   = in_sizes[0] / HIDDEN;   // 8192

    (void)hipFuncSetAttribute((const void*)gemm_kernel,
                              hipFuncAttributeMaxDynamicSharedMemorySize, LDS_BYTES);

    hipMemsetAsync(W, 0, (size_t)HIDDEN * HIDDEN * sizeof(float), stream);
    build_w_kernel<<<(nnz + 255) / 256, 256, 0, stream>>>(vals, idx, idx + nnz, W, nnz);

    convert_kernel<<<2048, 256, 0, stream>>>(xp, xpb, in_sizes[1] / 8);
    convert_kernel<<<2048, 256, 0, stream>>>(W, Wb, (HIDDEN * HIDDEN) / 8);

    dim3 grid((M / 256) * 8);   // 32 m-tiles x 8 n-tiles = 256 blocks
    gemm_kernel<<<grid, 512, LDS_BYTES, stream>>>(xc, xpb, Wb, alpha, out);
}

// Round 5
// 129.825 us; speedup vs baseline: 1.0694x; 1.0694x over previous
//
#include <hip/hip_runtime.h>
#include <hip/hip_bf16.h>

#define HIDDEN 2048
#define NT 64            // K tiles of 32
#define BK 32
// LDS: A 3x8KB + B 3x16KB + 1KB sink = 74752 B; 2 blocks/CU (149.5KB <= 160KB)
#define LDS_BYTES 74752

typedef __attribute__((ext_vector_type(8))) short bf16x8;
typedef __attribute__((ext_vector_type(4))) float f32x4;
typedef __attribute__((ext_vector_type(8))) unsigned short u16x8;

#define GLDS(gptr, lptr)                                                       \
    __builtin_amdgcn_global_load_lds(                                          \
        (const __attribute__((address_space(1))) void*)(gptr),                 \
        (__attribute__((address_space(3))) void*)(lptr), 16, 0, 0)

#define SCHED0() __builtin_amdgcn_sched_barrier(0)
#define BARRIER() __builtin_amdgcn_s_barrier()
#define LGKM0() do { asm volatile("s_waitcnt lgkmcnt(0)" ::: "memory"); SCHED0(); } while (0)
#define VMCNT(n) asm volatile("s_waitcnt vmcnt(" #n ")" ::: "memory")

// ---- Build dense W (f32) from COO with duplicate summing ----
__global__ void build_w_kernel(const float* __restrict__ vals,
                               const int* __restrict__ rows,
                               const int* __restrict__ cols,
                               float* __restrict__ W, int nnz) {
    int k = blockIdx.x * blockDim.x + threadIdx.x;
    if (k < nnz) atomicAdd(&W[(size_t)rows[k] * HIDDEN + cols[k]], vals[k]);
}

// ---- fused f32 -> bf16(trunc): [xp | W] in one launch ----
__global__ void convert_kernel(const float* __restrict__ xp,
                               unsigned short* __restrict__ xpb, int n8xp,
                               const float* __restrict__ W,
                               unsigned short* __restrict__ Wb, int n8w) {
    int i = blockIdx.x * blockDim.x + threadIdx.x;
    const int stride = gridDim.x * blockDim.x;
    const int total = n8xp + n8w;
    for (; i < total; i += stride) {
        const float* src = (i < n8xp) ? xp : W;
        unsigned short* dst = (i < n8xp) ? xpb : Wb;
        const int j = (i < n8xp) ? i : i - n8xp;
        f32x4 a = ((const f32x4*)src)[2 * j];
        f32x4 b = ((const f32x4*)src)[2 * j + 1];
        u16x8 h;
        #pragma unroll
        for (int k = 0; k < 4; ++k) {
            h[k]     = (unsigned short)(__float_as_uint(a[k]) >> 16);
            h[4 + k] = (unsigned short)(__float_as_uint(b[k]) >> 16);
        }
        ((u16x8*)dst)[j] = h;
    }
}

// ---- 128x256x32 8-wave GEMM, 3-buffer pipeline, 2 blocks/CU ----
__global__ __launch_bounds__(512, 4) void gemm_kernel(
    const float* __restrict__ xc,
    const unsigned short* __restrict__ xpb,   // bf16 [8192][2048]
    const unsigned short* __restrict__ Wb,    // bf16 [2048][2048]
    const float* __restrict__ alpha_p,
    float* __restrict__ out)
{
    extern __shared__ __align__(16) char lds[];
    char* const ldsA = lds;            // 3 x 8192  (buf: [128][32] bf16)
    char* const ldsB = lds + 24576;    // 3 x 16384 (buf: [256][32] bf16)
    char* const ldsX = lds + 73728;    // 1KB dummy sink

    const int tid  = threadIdx.x;
    const int lane = tid & 63;
    const int wave = tid >> 6;
    const int l15  = lane & 15;
    const int l4   = lane >> 4;

    // XCD-chunked bijective mapping: 512 blocks = 8 XCD x (8 m-tiles x 8 n-tiles)
    const int xcd = blockIdx.x & 7;
    const int loc = blockIdx.x >> 3;          // 0..63
    const int m0  = (xcd * 8 + (loc >> 3)) * 128;
    const int n0  = (loc & 7) * 256;

    const int wm = (wave >> 2) * 64;    // 2 M-waves
    const int wn = (wave & 3) * 64;     // 4 N-waves

    // ---- staging geometry: rows of 32 bf16 = 4 chunks of 16B ----
    // A tile (128x32): 512 chunks, 1/lane: chunk = wave*64+lane -> row=wave*16+q, slot=lane&3
    // B tile (256x32): 1024 chunks, 2/lane: rows wave*32+q and +16, same slot
    // T2 source swizzle: global slot = (lane&3) ^ (q&3); LDS dest stays linear.
    const int q  = lane >> 2;
    const int sw = (lane & 3) ^ (q & 3);
    const unsigned short* const gA = xpb + (size_t)(m0 + wave * 16 + q) * HIDDEN + sw * 8;
    const unsigned short* const gB = Wb  + (size_t)(n0 + wave * 32 + q) * HIDDEN + sw * 8;
    const int dAoff = (wave * 64 + lane) * 16;
    const int dBoff = (wave * 128 + lane) * 16;

    // stage tile t into LDS buffer `buf` (t and buf supplied separately)
#define STAGE_A(t, buf)  GLDS(gA + (size_t)(t) * BK, ldsA + (buf) * 8192 + dAoff)
#define STAGE_B0(t, buf) GLDS(gB + (size_t)(t) * BK, ldsB + (buf) * 16384 + dBoff)
#define STAGE_B1(t, buf) GLDS(gB + (size_t)(t) * BK + (size_t)16 * HIDDEN, ldsB + (buf) * 16384 + dBoff + 1024)
#define STAGE_DUMMY()    GLDS(gA, ldsX + lane * 16)

    // ---- ds_read addressing: row r holds global k-chunk (slot ^ (r&3)) at slot ----
    // frag addr: (row)*64 + ((l4 ^ (row&3))*16); row = base + l15 -> row&3 = l15&3
    const int kx   = (l4 ^ (l15 & 3)) * 16;
    const int aoff = (wm + l15) * 64 + kx;
    const int boff = (wn + l15) * 64 + kx;

    f32x4 acc[4][4] = {};   // [mi][nj] 16x16 fragments

    // ---- prologue: stage tiles 0 (buf0) and 1 (buf1); wait tile 0 ----
    STAGE_A(0, 0); STAGE_B0(0, 0); STAGE_B1(0, 0);
    STAGE_A(1, 1); STAGE_B0(1, 1); STAGE_B1(1, 1);
    VMCNT(3);
    SCHED0(); BARRIER(); SCHED0();

    int cur = 0, nxt = 1, prv = 2;   // read cur; stage t+2 into prv (==(t+2)%3)

    for (int tt = 0; tt < NT; ++tt) {
        const char* const Aw = ldsA + cur * 8192;
        const char* const Bw = ldsB + cur * 16384;
        const bool live = (tt + 2) < NT;

        bf16x8 a[4], b01[2], b23[2];

        // ======== Phase 1: read a0-3,b0-1 | stage A,B0(t+2) | MFMA nj=0,1 ========
        #pragma unroll
        for (int mi = 0; mi < 4; ++mi)
            a[mi] = *(const bf16x8*)(Aw + mi * 1024 + aoff);
        #pragma unroll
        for (int nj = 0; nj < 2; ++nj)
            b01[nj] = *(const bf16x8*)(Bw + nj * 1024 + boff);
        if (live) { STAGE_A(tt + 2, prv); STAGE_B0(tt + 2, prv); }
        else      { STAGE_DUMMY(); STAGE_DUMMY(); }
        SCHED0(); BARRIER();
        LGKM0();
        __builtin_amdgcn_s_setprio(1);
        #pragma unroll
        for (int mi = 0; mi < 4; ++mi)
            #pragma unroll
            for (int nj = 0; nj < 2; ++nj)
                acc[mi][nj] = __builtin_amdgcn_mfma_f32_16x16x32_bf16(a[mi], b01[nj], acc[mi][nj], 0, 0, 0);
        __builtin_amdgcn_s_setprio(0);
        SCHED0(); BARRIER(); SCHED0();

        // ======== Phase 2: read b2-3 | stage B1(t+2) | vmcnt(3) | MFMA nj=2,3 ========
        #pragma unroll
        for (int nj = 0; nj < 2; ++nj)
            b23[nj] = *(const bf16x8*)(Bw + (2 + nj) * 1024 + boff);
        if (live) STAGE_B1(tt + 2, prv); else STAGE_DUMMY();
        VMCNT(3);            // tile t+1 fully arrived; only t+2's 3 loads in flight
        SCHED0(); BARRIER();
        LGKM0();
        __builtin_amdgcn_s_setprio(1);
        #pragma unroll
        for (int mi = 0; mi < 4; ++mi)
            #pragma unroll
            for (int nj = 0; nj < 2; ++nj)
                acc[mi][2 + nj] = __builtin_amdgcn_mfma_f32_16x16x32_bf16(a[mi], b23[nj], acc[mi][2 + nj], 0, 0, 0);
        __builtin_amdgcn_s_setprio(0);
        SCHED0(); BARRIER(); SCHED0();

        const int t0 = cur; cur = nxt; nxt = prv; prv = t0;   // rotate 3 buffers
    }

    VMCNT(0);   // drain tail dummies

    // ---- epilogue: out = xc + alpha * acc ----
    // C/D map (m89-verified): col = lane&15, row = (lane>>4)*4 + reg
    const float alpha = alpha_p[0];
    #pragma unroll
    for (int mi = 0; mi < 4; ++mi) {
        #pragma unroll
        for (int r = 0; r < 4; ++r) {
            const int m = m0 + wm + mi * 16 + l4 * 4 + r;
            #pragma unroll
            for (int nj = 0; nj < 4; ++nj) {
                const int n = n0 + wn + nj * 16 + l15;
                const size_t o = (size_t)m * HIDDEN + n;
                out[o] = xc[o] + alpha * acc[mi][nj][r];
            }
        }
    }
#undef STAGE_A
#undef STAGE_B0
#undef STAGE_B1
#undef STAGE_DUMMY
}

extern "C" void kernel_launch(void* const* d_in, const int* in_sizes, int n_in,
                              void* d_out, int out_size, void* d_ws, size_t ws_size,
                              hipStream_t stream) {
    const float* xc    = (const float*)d_in[0];
    const float* xp    = (const float*)d_in[1];
    const float* alpha = (const float*)d_in[2];
    const float* vals  = (const float*)d_in[3];
    const int*   idx   = (const int*)d_in[4];
    float* out = (float*)d_out;

    float*          W   = (float*)d_ws;                                   // 16 MB
    unsigned short* Wb  = (unsigned short*)((char*)d_ws + (16 << 20));    //  8 MB
    unsigned short* xpb = (unsigned short*)((char*)d_ws + (24 << 20));    // 32 MB

    const int nnz = in_sizes[3];
    const int M   = in_sizes[0] / HIDDEN;   // 8192

    (void)hipFuncSetAttribute((const void*)gemm_kernel,
                              hipFuncAttributeMaxDynamicSharedMemorySize, LDS_BYTES);

    hipMemsetAsync(W, 0, (size_t)HIDDEN * HIDDEN * sizeof(float), stream);
    build_w_kernel<<<(nnz + 255) / 256, 256, 0, stream>>>(vals, idx, idx + nnz, W, nnz);

    convert_kernel<<<2048, 256, 0, stream>>>(xp, xpb, in_sizes[1] / 8,
                                             W, Wb, (HIDDEN * HIDDEN) / 8);

    dim3 grid((M / 128) * 8);   // 64 m-tiles x 8 n-tiles = 512 blocks (2/CU)
    gemm_kernel<<<grid, 512, LDS_BYTES, stream>>>(xc, xpb, Wb, alpha, out);
}

// Round 6
// 125.350 us; speedup vs baseline: 1.1075x; 1.0357x over previous
//
#include <hip/hip_runtime.h>
#include <hip/hip_bf16.h>

#define HIDDEN 2048
#define NT 32            // K tiles of 64
#define BK 64
#define LDS_BYTES 132096 // 2 bufs x (A 32KB + B 32KB) + 1KB dummy sink

typedef __attribute__((ext_vector_type(8))) short bf16x8;
typedef __attribute__((ext_vector_type(4))) float f32x4;
typedef __attribute__((ext_vector_type(8))) unsigned short u16x8;

#define GLDS(gptr, lptr)                                                       \
    __builtin_amdgcn_global_load_lds(                                          \
        (const __attribute__((address_space(1))) void*)(gptr),                 \
        (__attribute__((address_space(3))) void*)(lptr), 16, 0, 0)

#define SCHED0() __builtin_amdgcn_sched_barrier(0)
#define BARRIER() __builtin_amdgcn_s_barrier()
#define LGKMC(n) do { asm volatile("s_waitcnt lgkmcnt(" #n ")" ::: "memory"); SCHED0(); } while (0)
#define VMCNT(n)  do { asm volatile("s_waitcnt vmcnt(" #n ")" ::: "memory"); SCHED0(); } while (0)
#define PRIO1() __builtin_amdgcn_s_setprio(1)
#define PRIO0() __builtin_amdgcn_s_setprio(0)

// ---- Build dense W (f32) from COO with duplicate summing ----
__global__ void build_w_kernel(const float* __restrict__ vals,
                               const int* __restrict__ rows,
                               const int* __restrict__ cols,
                               float* __restrict__ W, int nnz) {
    int k = blockIdx.x * blockDim.x + threadIdx.x;
    if (k < nnz) atomicAdd(&W[(size_t)rows[k] * HIDDEN + cols[k]], vals[k]);
}

// ---- fused f32 -> bf16(trunc): [xp | W] in one launch ----
__global__ void convert_kernel(const float* __restrict__ xp,
                               unsigned short* __restrict__ xpb, int n8xp,
                               const float* __restrict__ W,
                               unsigned short* __restrict__ Wb, int n8w) {
    int i = blockIdx.x * blockDim.x + threadIdx.x;
    const int stride = gridDim.x * blockDim.x;
    const int total = n8xp + n8w;
    for (; i < total; i += stride) {
        const float* src = (i < n8xp) ? xp : W;
        unsigned short* dst = (i < n8xp) ? xpb : Wb;
        const int j = (i < n8xp) ? i : i - n8xp;
        f32x4 a = ((const f32x4*)src)[2 * j];
        f32x4 b = ((const f32x4*)src)[2 * j + 1];
        u16x8 h;
        #pragma unroll
        for (int k = 0; k < 4; ++k) {
            h[k]     = (unsigned short)(__float_as_uint(a[k]) >> 16);
            h[4 + k] = (unsigned short)(__float_as_uint(b[k]) >> 16);
        }
        ((u16x8*)dst)[j] = h;
    }
}

// ---- 256x256x64 8-wave GEMM, ds_read/MFMA software-pipelined ----
__global__ __launch_bounds__(512, 2) void gemm_kernel(
    const float* __restrict__ xc,
    const unsigned short* __restrict__ xpb,   // bf16 [8192][2048]
    const unsigned short* __restrict__ Wb,    // bf16 [2048][2048]
    const float* __restrict__ alpha_p,
    float* __restrict__ out)
{
    extern __shared__ __align__(16) char lds[];
    char* const ldsX = lds + 131072;    // 1KB dummy sink

    const int tid  = threadIdx.x;
    const int lane = tid & 63;
    const int wave = tid >> 6;
    const int l15  = lane & 15;
    const int l4   = lane >> 4;

    // XCD-chunked bijective mapping (keeps FETCH at compulsory ~82MB)
    const int xcd = blockIdx.x & 7;
    const int loc = blockIdx.x >> 3;          // 0..31
    const int m0  = (xcd * 4 + (loc >> 3)) * 256;
    const int n0  = (loc & 7) * 256;

    const int wm = (wave >> 2) * 128;   // 2 M-waves
    const int wn = (wave & 3) * 64;     // 4 N-waves

    // ---- staging: each wave owns 32 rows per matrix; 4 gloads A + 4 B ----
    // row = wave*32 + g*8 + srow, srow = lane>>3; slot = lane&7, src swizzled ^srow
    const int srow = lane >> 3;
    const int sw   = (lane & 7) ^ srow;
    const unsigned short* const gA = xpb + (size_t)(m0 + wave * 32 + srow) * HIDDEN + sw * 8;
    const unsigned short* const gB = Wb  + (size_t)(n0 + wave * 32 + srow) * HIDDEN + sw * 8;

#define STAGE(t)                                                               \
    do {                                                                       \
        const int _t = (t);                                                    \
        if (_t < NT) {                                                         \
            const size_t _o = (size_t)_t * BK;                                 \
            char* const _dA = lds + (_t & 1) * 65536 + wave * 4096;            \
            char* const _dB = _dA + 32768;                                     \
            GLDS(gA + _o,                _dA);                                 \
            GLDS(gA + _o +  8 * HIDDEN,  _dA + 1024);                          \
            GLDS(gA + _o + 16 * HIDDEN,  _dA + 2048);                          \
            GLDS(gA + _o + 24 * HIDDEN,  _dA + 3072);                          \
            GLDS(gB + _o,                _dB);                                 \
            GLDS(gB + _o +  8 * HIDDEN,  _dB + 1024);                          \
            GLDS(gB + _o + 16 * HIDDEN,  _dB + 2048);                          \
            GLDS(gB + _o + 24 * HIDDEN,  _dB + 3072);                          \
        } else {                                                               \
            GLDS(gA, ldsX); GLDS(gA, ldsX); GLDS(gA, ldsX); GLDS(gA, ldsX);    \
            GLDS(gA, ldsX); GLDS(gA, ldsX); GLDS(gA, ldsX); GLDS(gA, ldsX);    \
        }                                                                      \
    } while (0)

    // ---- ds_read addressing (verified r3: 0 bank conflicts) ----
    const int swz  = l15 & 7;
    const int sk0  = ((l4 + 0) ^ swz) * 16;
    const int sk1  = ((l4 + 4) ^ swz) * 16;
    const int rowb = l15 * 128;

    f32x4 acc[8][4] = {};
    bf16x8 a0[4][2], a1[4][2], b0[2][2], b1[2][2];

    // ---- prologue: stage tile 0, drain, barrier (one-time full drain) ----
    STAGE(0);
    VMCNT(0);
    SCHED0(); BARRIER(); SCHED0();

    for (int tt = 0; tt < NT; ++tt) {
        const char* const Ab = lds + (tt & 1) * 65536 + wm * 128;
        const char* const Bb = lds + (tt & 1) * 65536 + 32768 + wn * 128;

        // -- stage next tile early (max distance to the bottom vmcnt) --
        STAGE(tt + 1);
        SCHED0();

        // -- issue a0 reads (8) --
        #pragma unroll
        for (int mi = 0; mi < 4; ++mi) {
            a0[mi][0] = *(const bf16x8*)(Ab + mi * 2048 + rowb + sk0);
            a0[mi][1] = *(const bf16x8*)(Ab + mi * 2048 + rowb + sk1);
        }
        SCHED0();

        // -- Q4 of previous tile (old a1 x old b0) overlaps the reads --
        if (tt) {
            PRIO1();
            #pragma unroll
            for (int mi = 0; mi < 4; ++mi)
                #pragma unroll
                for (int nj = 0; nj < 2; ++nj) {
                    acc[4 + mi][nj] = __builtin_amdgcn_mfma_f32_16x16x32_bf16(a1[mi][0], b0[nj][0], acc[4 + mi][nj], 0, 0, 0);
                    acc[4 + mi][nj] = __builtin_amdgcn_mfma_f32_16x16x32_bf16(a1[mi][1], b0[nj][1], acc[4 + mi][nj], 0, 0, 0);
                }
            PRIO0();
        }
        SCHED0();

        // -- issue b0 reads (4); outstanding ds = 12 --
        #pragma unroll
        for (int nj = 0; nj < 2; ++nj) {
            b0[nj][0] = *(const bf16x8*)(Bb + nj * 2048 + rowb + sk0);
            b0[nj][1] = *(const bf16x8*)(Bb + nj * 2048 + rowb + sk1);
        }
        SCHED0();
        LGKMC(4);            // a0 done (b0 still flying)

        // -- issue b1 reads (4); outstanding = 8 --
        #pragma unroll
        for (int nj = 0; nj < 2; ++nj) {
            b1[nj][0] = *(const bf16x8*)(Bb + (2 + nj) * 2048 + rowb + sk0);
            b1[nj][1] = *(const bf16x8*)(Bb + (2 + nj) * 2048 + rowb + sk1);
        }
        SCHED0();
        LGKMC(4);            // b0 done (b1 flying)

        // -- Q1: a0 x b0 (b1 completes underneath) --
        PRIO1();
        #pragma unroll
        for (int mi = 0; mi < 4; ++mi)
            #pragma unroll
            for (int nj = 0; nj < 2; ++nj) {
                acc[mi][nj] = __builtin_amdgcn_mfma_f32_16x16x32_bf16(a0[mi][0], b0[nj][0], acc[mi][nj], 0, 0, 0);
                acc[mi][nj] = __builtin_amdgcn_mfma_f32_16x16x32_bf16(a0[mi][1], b0[nj][1], acc[mi][nj], 0, 0, 0);
            }
        PRIO0();
        SCHED0();

        // -- issue a1 reads (8); outstanding = 12 --
        #pragma unroll
        for (int mi = 0; mi < 4; ++mi) {
            a1[mi][0] = *(const bf16x8*)(Ab + (4 + mi) * 2048 + rowb + sk0);
            a1[mi][1] = *(const bf16x8*)(Ab + (4 + mi) * 2048 + rowb + sk1);
        }
        SCHED0();
        LGKMC(8);            // b1 done (a1 flying)

        // -- Q2: a0 x b1 (a1 completes underneath) --
        PRIO1();
        #pragma unroll
        for (int mi = 0; mi < 4; ++mi)
            #pragma unroll
            for (int nj = 0; nj < 2; ++nj) {
                acc[mi][2 + nj] = __builtin_amdgcn_mfma_f32_16x16x32_bf16(a0[mi][0], b1[nj][0], acc[mi][2 + nj], 0, 0, 0);
                acc[mi][2 + nj] = __builtin_amdgcn_mfma_f32_16x16x32_bf16(a0[mi][1], b1[nj][1], acc[mi][2 + nj], 0, 0, 0);
            }
        PRIO0();
        SCHED0();
        LGKMC(0);            // a1 done

        // -- Q3: a1 x b1 --
        PRIO1();
        #pragma unroll
        for (int mi = 0; mi < 4; ++mi)
            #pragma unroll
            for (int nj = 0; nj < 2; ++nj) {
                acc[4 + mi][2 + nj] = __builtin_amdgcn_mfma_f32_16x16x32_bf16(a1[mi][0], b1[nj][0], acc[4 + mi][2 + nj], 0, 0, 0);
                acc[4 + mi][2 + nj] = __builtin_amdgcn_mfma_f32_16x16x32_bf16(a1[mi][1], b1[nj][1], acc[4 + mi][2 + nj], 0, 0, 0);
            }
        PRIO0();
        SCHED0();

        // -- tile t+1 landed (issued ~2000cy ago, L2/L3-resident) --
        VMCNT(0);
        BARRIER(); SCHED0();
        // Q4 (a1 x b0) deferred to top of next iteration
    }

    // final deferred Q4
    PRIO1();
    #pragma unroll
    for (int mi = 0; mi < 4; ++mi)
        #pragma unroll
        for (int nj = 0; nj < 2; ++nj) {
            acc[4 + mi][nj] = __builtin_amdgcn_mfma_f32_16x16x32_bf16(a1[mi][0], b0[nj][0], acc[4 + mi][nj], 0, 0, 0);
            acc[4 + mi][nj] = __builtin_amdgcn_mfma_f32_16x16x32_bf16(a1[mi][1], b0[nj][1], acc[4 + mi][nj], 0, 0, 0);
        }
    PRIO0();

    // ---- epilogue: out = xc + alpha * acc ----
    const float alpha = alpha_p[0];
    #pragma unroll
    for (int mi = 0; mi < 8; ++mi) {
        #pragma unroll
        for (int r = 0; r < 4; ++r) {
            const int m = m0 + wm + mi * 16 + l4 * 4 + r;
            #pragma unroll
            for (int nj = 0; nj < 4; ++nj) {
                const int n = n0 + wn + nj * 16 + l15;
                const size_t o = (size_t)m * HIDDEN + n;
                out[o] = xc[o] + alpha * acc[mi][nj][r];
            }
        }
    }
#undef STAGE
}

extern "C" void kernel_launch(void* const* d_in, const int* in_sizes, int n_in,
                              void* d_out, int out_size, void* d_ws, size_t ws_size,
                              hipStream_t stream) {
    const float* xc    = (const float*)d_in[0];
    const float* xp    = (const float*)d_in[1];
    const float* alpha = (const float*)d_in[2];
    const float* vals  = (const float*)d_in[3];
    const int*   idx   = (const int*)d_in[4];
    float* out = (float*)d_out;

    float*          W   = (float*)d_ws;                                   // 16 MB
    unsigned short* Wb  = (unsigned short*)((char*)d_ws + (16 << 20));    //  8 MB
    unsigned short* xpb = (unsigned short*)((char*)d_ws + (24 << 20));    // 32 MB

    const int nnz = in_sizes[3];
    const int M   = in_sizes[0] / HIDDEN;   // 8192

    (void)hipFuncSetAttribute((const void*)gemm_kernel,
                              hipFuncAttributeMaxDynamicSharedMemorySize, LDS_BYTES);

    hipMemsetAsync(W, 0, (size_t)HIDDEN * HIDDEN * sizeof(float), stream);
    build_w_kernel<<<(nnz + 255) / 256, 256, 0, stream>>>(vals, idx, idx + nnz, W, nnz);

    convert_kernel<<<2048, 256, 0, stream>>>(xp, xpb, in_sizes[1] / 8,
                                             W, Wb, (HIDDEN * HIDDEN) / 8);

    dim3 grid((M / 256) * 8);   // 32 m-tiles x 8 n-tiles = 256 blocks
    gemm_kernel<<<grid, 512, LDS_BYTES, stream>>>(xc, xpb, Wb, alpha, out);
}

// Round 7
// 94.771 us; speedup vs baseline: 1.4649x; 1.3227x over previous
//
#include <hip/hip_runtime.h>
#include <hip/hip_bf16.h>
#include <hip/hip_fp8.h>

#define HIDDEN 2048
#define NT 16            // K tiles of 128 (fp8)
#define BKB 128          // K-tile bytes per row
#define LDS_BYTES 132096 // 2 bufs x (A 32KB + B 32KB) + 1KB dummy sink

typedef __attribute__((ext_vector_type(4))) float f32x4;
typedef __attribute__((ext_vector_type(4))) int   i32x4;
typedef __attribute__((ext_vector_type(8))) int   i32x8;

#define GLDS(gptr, lptr)                                                       \
    __builtin_amdgcn_global_load_lds(                                          \
        (const __attribute__((address_space(1))) void*)(gptr),                 \
        (__attribute__((address_space(3))) void*)(lptr), 16, 0, 0)

#define SCHED0() __builtin_amdgcn_sched_barrier(0)
#define BARRIER() __builtin_amdgcn_s_barrier()
#define LGKMC(n) do { asm volatile("s_waitcnt lgkmcnt(" #n ")" ::: "memory"); SCHED0(); } while (0)
#define VMCNT(n)  do { asm volatile("s_waitcnt vmcnt(" #n ")" ::: "memory"); SCHED0(); } while (0)
#define PRIO1() __builtin_amdgcn_s_setprio(1)
#define PRIO0() __builtin_amdgcn_s_setprio(0)

// uniform 1.0 scales (E8M0 exponent 127 in every byte -> opsel-proof)
#define SCALE1 0x7F7F7F7F

#define MFMA(a, b, c)                                                          \
    __builtin_amdgcn_mfma_scale_f32_16x16x128_f8f6f4(                          \
        (a), (b), (c), 0 /*cbsz: A=fp8 e4m3*/, 0 /*blgp: B=fp8 e4m3*/,         \
        0, SCALE1, 0, SCALE1)

// ---- Build dense W (f32) from COO with duplicate summing ----
__global__ void build_w_kernel(const float* __restrict__ vals,
                               const int* __restrict__ rows,
                               const int* __restrict__ cols,
                               float* __restrict__ W, int nnz) {
    int k = blockIdx.x * blockDim.x + threadIdx.x;
    if (k < nnz) atomicAdd(&W[(size_t)rows[k] * HIDDEN + cols[k]], vals[k]);
}

// ---- fused f32 -> fp8 e4m3 (RNE, saturating): [xp | W*512] ----
__global__ void convert_kernel(const float* __restrict__ xp,
                               unsigned char* __restrict__ xp8, int n8xp,
                               const float* __restrict__ W,
                               unsigned char* __restrict__ W8, int n8w) {
    int i = blockIdx.x * blockDim.x + threadIdx.x;
    const int stride = gridDim.x * blockDim.x;
    const int total = n8xp + n8w;
    for (; i < total; i += stride) {
        const bool isxp = (i < n8xp);
        const float* src = isxp ? xp : W;
        unsigned char* dst = isxp ? xp8 : W8;
        const float scale = isxp ? 1.0f : 512.0f;   // lift W out of subnormal range
        const int j = isxp ? i : i - n8xp;
        f32x4 a = ((const f32x4*)src)[2 * j];
        f32x4 b = ((const f32x4*)src)[2 * j + 1];
        union { unsigned char b8[8]; uint2 v; } u;
        #pragma unroll
        for (int k = 0; k < 4; ++k) {
            u.b8[k]     = __hip_fp8_e4m3(a[k] * scale).__x;
            u.b8[4 + k] = __hip_fp8_e4m3(b[k] * scale).__x;
        }
        ((uint2*)dst)[j] = u.v;
    }
}

// ---- 256x256xK128 8-wave MX-fp8 GEMM: out = xc + alpha * (xp @ W^T) ----
__global__ __launch_bounds__(512, 2) void gemm_kernel(
    const float* __restrict__ xc,
    const unsigned char* __restrict__ xp8,   // e4m3 [8192][2048]
    const unsigned char* __restrict__ w8,    // e4m3 [2048][2048], values x512
    const float* __restrict__ alpha_p,
    float* __restrict__ out)
{
    extern __shared__ __align__(16) char lds[];
    char* const ldsX = lds + 131072;    // 1KB dummy sink

    const int tid  = threadIdx.x;
    const int lane = tid & 63;
    const int wave = tid >> 6;
    const int l15  = lane & 15;
    const int l4   = lane >> 4;

    // XCD-chunked bijective mapping (FETCH stays ~compulsory)
    const int xcd = blockIdx.x & 7;
    const int loc = blockIdx.x >> 3;          // 0..31
    const int m0  = (xcd * 4 + (loc >> 3)) * 256;
    const int n0  = (loc & 7) * 256;

    const int wm = (wave >> 2) * 128;   // 2 M-waves
    const int wn = (wave & 3) * 64;     // 4 N-waves

    // ---- staging: tile 256 rows x 128 B; wave owns 32 rows; 4 gloads each A/B ----
    // srow = lane>>3; slot = lane&7; T2 swizzle on the global SOURCE chunk.
    const int srow = lane >> 3;
    const int sw   = (lane & 7) ^ srow;
    const unsigned char* const gA = xp8 + (size_t)(m0 + wave * 32 + srow) * HIDDEN + sw * 16;
    const unsigned char* const gB = w8  + (size_t)(n0 + wave * 32 + srow) * HIDDEN + sw * 16;

#define STAGE(t)                                                               \
    do {                                                                       \
        const int _t = (t);                                                    \
        if (_t < NT) {                                                         \
            const size_t _o = (size_t)_t * BKB;                                \
            char* const _dA = lds + (_t & 1) * 65536 + wave * 4096;            \
            char* const _dB = _dA + 32768;                                     \
            GLDS(gA + _o,                _dA);                                 \
            GLDS(gA + _o +  8 * HIDDEN,  _dA + 1024);                          \
            GLDS(gA + _o + 16 * HIDDEN,  _dA + 2048);                          \
            GLDS(gA + _o + 24 * HIDDEN,  _dA + 3072);                          \
            GLDS(gB + _o,                _dB);                                 \
            GLDS(gB + _o +  8 * HIDDEN,  _dB + 1024);                          \
            GLDS(gB + _o + 16 * HIDDEN,  _dB + 2048);                          \
            GLDS(gB + _o + 24 * HIDDEN,  _dB + 3072);                          \
        } else {                                                               \
            GLDS(gA, ldsX); GLDS(gA, ldsX); GLDS(gA, ldsX); GLDS(gA, ldsX);    \
            GLDS(gA, ldsX); GLDS(gA, ldsX); GLDS(gA, ldsX); GLDS(gA, ldsX);    \
        }                                                                      \
    } while (0)

    // ---- ds_read addressing ----
    // frag: lane holds row (base + l15), k-bytes [l4*32, l4*32+32) = chunks 2*l4, 2*l4+1
    // stored LDS chunk = global chunk ^ (row&7); row&7 == l15&7
    const int swz  = l15 & 7;
    const int c0   = ((2 * l4 + 0) ^ swz) * 16;
    const int c1   = ((2 * l4 + 1) ^ swz) * 16;
    const int rowb = l15 * 128;

#define LDFRAG(dst, base)                                                      \
    do {                                                                       \
        i32x4 _lo = *(const i32x4*)((base) + c0);                              \
        i32x4 _hi = *(const i32x4*)((base) + c1);                              \
        (dst) = __builtin_shufflevector(_lo, _hi, 0, 1, 2, 3, 4, 5, 6, 7);     \
    } while (0)

    f32x4 acc[8][4] = {};
    i32x8 a0[4], a1[4], b01[2], b23[2];

    // ---- prologue ----
    STAGE(0);
    VMCNT(0);
    SCHED0(); BARRIER(); SCHED0();

    for (int tt = 0; tt < NT; ++tt) {
        const char* const Ab = lds + (tt & 1) * 65536 + wm * 128;
        const char* const Bb = lds + (tt & 1) * 65536 + 32768 + wn * 128;

        // -- stage next tile early --
        STAGE(tt + 1);
        SCHED0();

        // -- issue a0 reads (8 x b128) --
        #pragma unroll
        for (int mi = 0; mi < 4; ++mi)
            LDFRAG(a0[mi], Ab + mi * 2048 + rowb);
        SCHED0();

        // -- Q4 of previous tile overlaps the reads --
        if (tt) {
            PRIO1();
            #pragma unroll
            for (int mi = 0; mi < 4; ++mi)
                #pragma unroll
                for (int nj = 0; nj < 2; ++nj)
                    acc[4 + mi][nj] = MFMA(a1[mi], b01[nj], acc[4 + mi][nj]);
            PRIO0();
        }
        SCHED0();

        // -- issue b01 reads (4); outstanding = 12 --
        #pragma unroll
        for (int nj = 0; nj < 2; ++nj)
            LDFRAG(b01[nj], Bb + nj * 2048 + rowb);
        SCHED0();
        LGKMC(4);            // a0 done (b01 flying)

        // -- issue b23 reads (4); outstanding = 8 --
        #pragma unroll
        for (int nj = 0; nj < 2; ++nj)
            LDFRAG(b23[nj], Bb + (2 + nj) * 2048 + rowb);
        SCHED0();
        LGKMC(4);            // b01 done (b23 flying)

        // -- Q1: a0 x b01 --
        PRIO1();
        #pragma unroll
        for (int mi = 0; mi < 4; ++mi)
            #pragma unroll
            for (int nj = 0; nj < 2; ++nj)
                acc[mi][nj] = MFMA(a0[mi], b01[nj], acc[mi][nj]);
        PRIO0();
        SCHED0();

        // -- issue a1 reads (8); outstanding = 12 --
        #pragma unroll
        for (int mi = 0; mi < 4; ++mi)
            LDFRAG(a1[mi], Ab + (4 + mi) * 2048 + rowb);
        SCHED0();
        LGKMC(8);            // b23 done (a1 flying)

        // -- Q2: a0 x b23 --
        PRIO1();
        #pragma unroll
        for (int mi = 0; mi < 4; ++mi)
            #pragma unroll
            for (int nj = 0; nj < 2; ++nj)
                acc[mi][2 + nj] = MFMA(a0[mi], b23[nj], acc[mi][2 + nj]);
        PRIO0();
        SCHED0();
        LGKMC(0);            // a1 done

        // -- Q3: a1 x b23 --
        PRIO1();
        #pragma unroll
        for (int mi = 0; mi < 4; ++mi)
            #pragma unroll
            for (int nj = 0; nj < 2; ++nj)
                acc[4 + mi][2 + nj] = MFMA(a1[mi], b23[nj], acc[4 + mi][2 + nj]);
        PRIO0();
        SCHED0();

        VMCNT(0);            // tile t+1 landed (issued a full tile ago)
        BARRIER(); SCHED0();
        // Q4 (a1 x b01) deferred to next iteration top
    }

    // final deferred Q4
    PRIO1();
    #pragma unroll
    for (int mi = 0; mi < 4; ++mi)
        #pragma unroll
        for (int nj = 0; nj < 2; ++nj)
            acc[4 + mi][nj] = MFMA(a1[mi], b01[nj], acc[4 + mi][nj]);
    PRIO0();

    // ---- epilogue: out = xc + (alpha/512) * acc   (W was pre-scaled x512) ----
    const float alpha = alpha_p[0] * (1.0f / 512.0f);
    #pragma unroll
    for (int mi = 0; mi < 8; ++mi) {
        #pragma unroll
        for (int r = 0; r < 4; ++r) {
            const int m = m0 + wm + mi * 16 + l4 * 4 + r;
            #pragma unroll
            for (int nj = 0; nj < 4; ++nj) {
                const int n = n0 + wn + nj * 16 + l15;
                const size_t o = (size_t)m * HIDDEN + n;
                out[o] = xc[o] + alpha * acc[mi][nj][r];
            }
        }
    }
#undef STAGE
#undef LDFRAG
}

extern "C" void kernel_launch(void* const* d_in, const int* in_sizes, int n_in,
                              void* d_out, int out_size, void* d_ws, size_t ws_size,
                              hipStream_t stream) {
    const float* xc    = (const float*)d_in[0];
    const float* xp    = (const float*)d_in[1];
    const float* alpha = (const float*)d_in[2];
    const float* vals  = (const float*)d_in[3];
    const int*   idx   = (const int*)d_in[4];
    float* out = (float*)d_out;

    float*         W   = (float*)d_ws;                                  // 16 MB
    unsigned char* W8  = (unsigned char*)((char*)d_ws + (16 << 20));    //  4 MB
    unsigned char* xp8 = (unsigned char*)((char*)d_ws + (20 << 20));    // 16.8 MB

    const int nnz = in_sizes[3];
    const int M   = in_sizes[0] / HIDDEN;   // 8192

    (void)hipFuncSetAttribute((const void*)gemm_kernel,
                              hipFuncAttributeMaxDynamicSharedMemorySize, LDS_BYTES);

    hipMemsetAsync(W, 0, (size_t)HIDDEN * HIDDEN * sizeof(float), stream);
    build_w_kernel<<<(nnz + 255) / 256, 256, 0, stream>>>(vals, idx, idx + nnz, W, nnz);

    convert_kernel<<<2048, 256, 0, stream>>>(xp, xp8, in_sizes[1] / 8,
                                             W, W8, (HIDDEN * HIDDEN) / 8);

    dim3 grid((M / 256) * 8);   // 32 m-tiles x 8 n-tiles = 256 blocks
    gemm_kernel<<<grid, 512, LDS_BYTES, stream>>>(xc, xp8, W8, alpha, out);
}

// Round 8
// 84.743 us; speedup vs baseline: 1.6383x; 1.1183x over previous
//
#include <hip/hip_runtime.h>
#include <hip/hip_bf16.h>

#define HIDDEN 2048
#define NT 16            // K tiles of 128 (fp4: 64 B per row per tile)
#define LDS_BYTES 66560  // 2 bufs x (A 16KB + B 16KB) + 1KB dummy sink

typedef __attribute__((ext_vector_type(4))) float f32x4;
typedef __attribute__((ext_vector_type(4))) int   i32x4;
typedef __attribute__((ext_vector_type(8))) int   i32x8;

#define GLDS(gptr, lptr)                                                       \
    __builtin_amdgcn_global_load_lds(                                          \
        (const __attribute__((address_space(1))) void*)(gptr),                 \
        (__attribute__((address_space(3))) void*)(lptr), 16, 0, 0)

#define SCHED0() __builtin_amdgcn_sched_barrier(0)
#define BARRIER() __builtin_amdgcn_s_barrier()
#define LGKMC(n) do { asm volatile("s_waitcnt lgkmcnt(" #n ")" ::: "memory"); SCHED0(); } while (0)
#define VMCNT(n)  do { asm volatile("s_waitcnt vmcnt(" #n ")" ::: "memory"); SCHED0(); } while (0)
#define PRIO1() __builtin_amdgcn_s_setprio(1)
#define PRIO0() __builtin_amdgcn_s_setprio(0)

#define SCALE1 0x7F7F7F7F   // E8M0 = 1.0 in every byte

// FMT code 4 = fp4 (e2m1) for both A (cbsz) and B (blgp)
#define MFMA4(a, b, c)                                                         \
    __builtin_amdgcn_mfma_scale_f32_16x16x128_f8f6f4(                          \
        (a), (b), (c), 4, 4, 0, SCALE1, 0, SCALE1)

// ---- Build dense W (f32) from COO with duplicate summing ----
__global__ void build_w_kernel(const float* __restrict__ vals,
                               const int* __restrict__ rows,
                               const int* __restrict__ cols,
                               float* __restrict__ W, int nnz) {
    int k = blockIdx.x * blockDim.x + threadIdx.x;
    if (k < nnz) atomicAdd(&W[(size_t)rows[k] * HIDDEN + cols[k]], vals[k]);
}

// ---- e2m1 quantize (RNE by midpoint thresholds) ----
__device__ __forceinline__ unsigned q_e2m1(float x) {
    float v = fabsf(x);
    unsigned n;
    if      (v < 0.25f) n = 0;
    else if (v < 0.75f) n = 1;   // 0.5
    else if (v < 1.25f) n = 2;   // 1.0
    else if (v < 1.75f) n = 3;   // 1.5
    else if (v < 2.5f)  n = 4;   // 2
    else if (v < 3.5f)  n = 5;   // 3
    else if (v < 5.0f)  n = 6;   // 4
    else                n = 7;   // 6
    return n | (x < 0.0f ? 8u : 0u);
}

// ---- fused f32 -> fp4 e2m1 packed: [xp | W*1024]; 8 elems -> 1 uint ----
__global__ void convert_kernel(const float* __restrict__ xp,
                               unsigned int* __restrict__ xp4, int n8xp,
                               const float* __restrict__ W,
                               unsigned int* __restrict__ W4, int n8w) {
    int i = blockIdx.x * blockDim.x + threadIdx.x;
    const int stride = gridDim.x * blockDim.x;
    const int total = n8xp + n8w;
    for (; i < total; i += stride) {
        const bool isxp = (i < n8xp);
        const float* src = isxp ? xp : W;
        unsigned int* dst = isxp ? xp4 : W4;
        const float scale = isxp ? 1.0f : 1024.0f;
        const int j = isxp ? i : i - n8xp;
        f32x4 a = ((const f32x4*)src)[2 * j];
        f32x4 b = ((const f32x4*)src)[2 * j + 1];
        unsigned int w = 0;
        #pragma unroll
        for (int k = 0; k < 4; ++k) {
            w |= q_e2m1(a[k] * scale) << (4 * k);
            w |= q_e2m1(b[k] * scale) << (16 + 4 * k);
        }
        dst[j] = w;
    }
}

// ---- 256x256xK128 8-wave MX-fp4 GEMM: out = xc + alpha * (xp @ W^T) ----
__global__ __launch_bounds__(512, 2) void gemm_kernel(
    const float* __restrict__ xc,
    const unsigned char* __restrict__ xp4,   // fp4 [8192][2048/2 B]
    const unsigned char* __restrict__ w4,    // fp4 [2048][1024 B], values x1024
    const float* __restrict__ alpha_p,
    float* __restrict__ out)
{
    extern __shared__ __align__(16) char lds[];
    char* const ldsX = lds + 65536;     // 1KB dummy sink

    const int tid  = threadIdx.x;
    const int lane = tid & 63;
    const int wave = tid >> 6;
    const int l15  = lane & 15;
    const int l4   = lane >> 4;

    // XCD-chunked bijective mapping
    const int xcd = blockIdx.x & 7;
    const int loc = blockIdx.x >> 3;          // 0..31
    const int m0  = (xcd * 4 + (loc >> 3)) * 256;
    const int n0  = (loc & 7) * 256;

    const int wm = (wave >> 2) * 128;   // 2 M-waves
    const int wn = (wave & 3) * 64;     // 4 N-waves

    // ---- staging: tile 256 rows x 64 B (fp4). wave owns 32 rows = 2 gloads/matrix.
    // gload g: rows wave*32 + g*16 + (lane>>2); 16B-chunk = lane&3.
    // T2 source swizzle: chunk' = (lane&3) ^ ((srow>>1)&3)  (matches read side)
    const int srow = lane >> 2;               // 0..15
    const int sw   = (lane & 3) ^ ((srow >> 1) & 3);
    const unsigned char* const gA = xp4 + (size_t)(m0 + wave * 32 + srow) * 1024 + sw * 16;
    const unsigned char* const gB = w4  + (size_t)(n0 + wave * 32 + srow) * 1024 + sw * 16;

#define STAGE(t)                                                               \
    do {                                                                       \
        const int _t = (t);                                                    \
        if (_t < NT) {                                                         \
            const size_t _o = (size_t)_t * 64;                                 \
            char* const _dA = lds + (_t & 1) * 32768 + wave * 2048 + lane * 16;\
            char* const _dB = _dA + 16384;                                     \
            GLDS(gA + _o,          _dA);                                       \
            GLDS(gA + _o + 16384,  _dA + 1024);   /* +16 rows (g=1) */         \
            GLDS(gB + _o,          _dB);                                       \
            GLDS(gB + _o + 16384,  _dB + 1024);                                \
        } else {                                                               \
            GLDS(gA, ldsX); GLDS(gA, ldsX); GLDS(gA, ldsX); GLDS(gA, ldsX);    \
        }                                                                      \
    } while (0)

    // ---- ds_read: lane reads row (base + l15), k-chunk l4 (16 B = full frag) ----
    // stored chunk = global chunk ^ ((row&15)>>1 & 3); row&15 == l15
    const int kx   = (l4 ^ ((l15 >> 1) & 3)) * 16;
    const int rowb = l15 * 64;

#define LDFRAG(dst, base)                                                      \
    do {                                                                       \
        i32x4 _v = *(const i32x4*)((base) + rowb + kx);                        \
        (dst) = __builtin_shufflevector(_v, (i32x4){0, 0, 0, 0},               \
                                        0, 1, 2, 3, 4, 5, 6, 7);               \
    } while (0)

    f32x4 acc[8][4] = {};
    i32x8 a0[4], a1[4], b01[2], b23[2];

    // ---- prologue ----
    STAGE(0);
    VMCNT(0);
    SCHED0(); BARRIER(); SCHED0();

    for (int tt = 0; tt < NT; ++tt) {
        const char* const Ab = lds + (tt & 1) * 32768 + wm * 64;
        const char* const Bb = lds + (tt & 1) * 32768 + 16384 + wn * 64;

        // -- stage next tile early --
        STAGE(tt + 1);
        SCHED0();

        // -- issue a0 reads (4 x b128) --
        #pragma unroll
        for (int mi = 0; mi < 4; ++mi)
            LDFRAG(a0[mi], Ab + mi * 1024);
        SCHED0();

        // -- Q4 of previous tile overlaps the reads --
        if (tt) {
            PRIO1();
            #pragma unroll
            for (int mi = 0; mi < 4; ++mi)
                #pragma unroll
                for (int nj = 0; nj < 2; ++nj)
                    acc[4 + mi][nj] = MFMA4(a1[mi], b01[nj], acc[4 + mi][nj]);
            PRIO0();
        }
        SCHED0();

        // -- issue b01 reads (2); outstanding = 6 --
        #pragma unroll
        for (int nj = 0; nj < 2; ++nj)
            LDFRAG(b01[nj], Bb + nj * 1024);
        SCHED0();
        LGKMC(2);            // a0 done (b01 flying)

        // -- issue b23 reads (2); outstanding = 4 --
        #pragma unroll
        for (int nj = 0; nj < 2; ++nj)
            LDFRAG(b23[nj], Bb + (2 + nj) * 1024);
        SCHED0();
        LGKMC(2);            // b01 done (b23 flying)

        // -- Q1: a0 x b01 --
        PRIO1();
        #pragma unroll
        for (int mi = 0; mi < 4; ++mi)
            #pragma unroll
            for (int nj = 0; nj < 2; ++nj)
                acc[mi][nj] = MFMA4(a0[mi], b01[nj], acc[mi][nj]);
        PRIO0();
        SCHED0();

        // -- issue a1 reads (4); outstanding = 6 --
        #pragma unroll
        for (int mi = 0; mi < 4; ++mi)
            LDFRAG(a1[mi], Ab + (4 + mi) * 1024);
        SCHED0();
        LGKMC(4);            // b23 done (a1 flying)

        // -- Q2: a0 x b23 --
        PRIO1();
        #pragma unroll
        for (int mi = 0; mi < 4; ++mi)
            #pragma unroll
            for (int nj = 0; nj < 2; ++nj)
                acc[mi][2 + nj] = MFMA4(a0[mi], b23[nj], acc[mi][2 + nj]);
        PRIO0();
        SCHED0();
        LGKMC(0);            // a1 done

        // -- Q3: a1 x b23 --
        PRIO1();
        #pragma unroll
        for (int mi = 0; mi < 4; ++mi)
            #pragma unroll
            for (int nj = 0; nj < 2; ++nj)
                acc[4 + mi][2 + nj] = MFMA4(a1[mi], b23[nj], acc[4 + mi][2 + nj]);
        PRIO0();
        SCHED0();

        VMCNT(0);            // tile t+1 landed (issued a full tile body ago)
        BARRIER(); SCHED0();
        // Q4 (a1 x b01) deferred to next iteration top
    }

    // final deferred Q4
    PRIO1();
    #pragma unroll
    for (int mi = 0; mi < 4; ++mi)
        #pragma unroll
        for (int nj = 0; nj < 2; ++nj)
            acc[4 + mi][nj] = MFMA4(a1[mi], b01[nj], acc[4 + mi][nj]);
    PRIO0();

    // ---- epilogue: out = xc + (alpha/1024) * acc   (W pre-scaled x1024) ----
    const float alpha = alpha_p[0] * (1.0f / 1024.0f);
    #pragma unroll
    for (int mi = 0; mi < 8; ++mi) {
        #pragma unroll
        for (int r = 0; r < 4; ++r) {
            const int m = m0 + wm + mi * 16 + l4 * 4 + r;
            #pragma unroll
            for (int nj = 0; nj < 4; ++nj) {
                const int n = n0 + wn + nj * 16 + l15;
                const size_t o = (size_t)m * HIDDEN + n;
                out[o] = xc[o] + alpha * acc[mi][nj][r];
            }
        }
    }
#undef STAGE
#undef LDFRAG
}

extern "C" void kernel_launch(void* const* d_in, const int* in_sizes, int n_in,
                              void* d_out, int out_size, void* d_ws, size_t ws_size,
                              hipStream_t stream) {
    const float* xc    = (const float*)d_in[0];
    const float* xp    = (const float*)d_in[1];
    const float* alpha = (const float*)d_in[2];
    const float* vals  = (const float*)d_in[3];
    const int*   idx   = (const int*)d_in[4];
    float* out = (float*)d_out;

    float*         W   = (float*)d_ws;                                  // 16 MB
    unsigned char* W4  = (unsigned char*)((char*)d_ws + (16 << 20));    //  2 MB
    unsigned char* xp4 = (unsigned char*)((char*)d_ws + (18 << 20));    // 8.4 MB

    const int nnz = in_sizes[3];
    const int M   = in_sizes[0] / HIDDEN;   // 8192

    (void)hipFuncSetAttribute((const void*)gemm_kernel,
                              hipFuncAttributeMaxDynamicSharedMemorySize, LDS_BYTES);

    hipMemsetAsync(W, 0, (size_t)HIDDEN * HIDDEN * sizeof(float), stream);
    build_w_kernel<<<(nnz + 255) / 256, 256, 0, stream>>>(vals, idx, idx + nnz, W, nnz);

    convert_kernel<<<2048, 256, 0, stream>>>(xp, (unsigned int*)xp4, in_sizes[1] / 8,
                                             W, (unsigned int*)W4, (HIDDEN * HIDDEN) / 8);

    dim3 grid((M / 256) * 8);   // 32 m-tiles x 8 n-tiles = 256 blocks
    gemm_kernel<<<grid, 512, LDS_BYTES, stream>>>(xc, xp4, W4, alpha, out);
}